// Round 1
// baseline (297.100 us; speedup 1.0000x reference)
//
#include <hip/hip_runtime.h>
#include <hip/hip_bf16.h>

// SparseEmbedding: out[b,d] = sum_n vals[b,n] * kernel[idx[b,n], d] + bias[d]
// B=4096, NNZ=32, V=1e6, D=64, all fp32 (idx int32).
//
// Layout: 16 lanes per batch row, each lane owns a float4 slice of the 64-dim
// output. One gather load instruction per wave covers 4 rows x 256B = 1 KB
// (16 B/lane coalescing sweet spot). Full unroll over NNZ=32 gives deep
// independent-load ILP to hide ~900-cycle HBM gather latency at only
// 4 waves/CU occupancy.

#define B_BATCH 4096
#define NNZ 32
#define DIM 64
#define LANES_PER_ROW 16  // DIM/4 floats per lane

__global__ __launch_bounds__(256) void sparse_embed_kernel(
    const int* __restrict__ idx,
    const float* __restrict__ vals,
    const float* __restrict__ kern,
    const float* __restrict__ bias,
    float* __restrict__ out)
{
    const int tid  = blockIdx.x * blockDim.x + threadIdx.x;
    const int row  = tid >> 4;        // batch row
    const int lane = tid & 15;        // 4-float slice within the 64-dim row
    if (row >= B_BATCH) return;

    const int*   irow = idx  + row * NNZ;
    const float* vrow = vals + row * NNZ;

    float4 acc = make_float4(0.f, 0.f, 0.f, 0.f);

    #pragma unroll
    for (int n = 0; n < NNZ; ++n) {
        const int   id = irow[n];
        const float v  = vrow[n];
        const float4 k = *reinterpret_cast<const float4*>(
            kern + (size_t)id * DIM + lane * 4);
        acc.x += v * k.x;
        acc.y += v * k.y;
        acc.z += v * k.z;
        acc.w += v * k.w;
    }

    const float4 b4 = *reinterpret_cast<const float4*>(bias + lane * 4);
    acc.x += b4.x;
    acc.y += b4.y;
    acc.z += b4.z;
    acc.w += b4.w;

    *reinterpret_cast<float4*>(out + (size_t)row * DIM + lane * 4) = acc;
}

extern "C" void kernel_launch(void* const* d_in, const int* in_sizes, int n_in,
                              void* d_out, int out_size, void* d_ws, size_t ws_size,
                              hipStream_t stream) {
    const int*   idx  = (const int*)  d_in[0];
    const float* vals = (const float*)d_in[1];
    const float* kern = (const float*)d_in[2];
    const float* bias = (const float*)d_in[3];
    float* out = (float*)d_out;

    const int threads = 256;
    const int total   = B_BATCH * LANES_PER_ROW;   // 65536 threads
    const int blocks  = (total + threads - 1) / threads;  // 256 blocks

    sparse_embed_kernel<<<blocks, threads, 0, stream>>>(idx, vals, kern, bias, out);
}